// Round 4
// baseline (1665.604 us; speedup 1.0000x reference)
//
#include <hip/hip_runtime.h>
#include <hip/hip_bf16.h>
#include <math.h>

typedef __attribute__((ext_vector_type(4))) float f32x4;
typedef __attribute__((ext_vector_type(8))) __bf16 bf16x8;

#define GAS __attribute__((address_space(1)))
#define LAS __attribute__((address_space(3)))

static __device__ __forceinline__ void g2lds16(const void* g, void* l) {
    __builtin_amdgcn_global_load_lds((const GAS void*)g, (LAS void*)l, 16, 0, 0);
}
static __device__ __forceinline__ f32x4 mfma16(bf16x8 a, bf16x8 b, f32x4 c) {
    return __builtin_amdgcn_mfma_f32_16x16x32_bf16(a, b, c, 0, 0, 0);
}

// ---------------------------------------------------------------------------
// Transpose + convert: W (K x N, f32 row-major) -> Wt (N x K, bf16 row-major)
// grid: (N/64, K/64), block 256
// ---------------------------------------------------------------------------
__global__ __launch_bounds__(256) void transpose_cvt(
    const float* __restrict__ W, __hip_bfloat16* __restrict__ Wt, int K, int N)
{
    __shared__ float tile[64][65];
    int k0 = blockIdx.y * 64, n0 = blockIdx.x * 64;
    int t = threadIdx.x;
#pragma unroll
    for (int i = 0; i < 16; ++i) {
        int idx = t + i * 256;
        int r = idx >> 6, cc = idx & 63;
        tile[r][cc] = W[(size_t)(k0 + r) * N + n0 + cc];
    }
    __syncthreads();
#pragma unroll
    for (int i = 0; i < 8; ++i) {
        int idx = t + i * 256;
        int n = idx >> 5, kp = idx & 31;
        __hip_bfloat162 u;
        u.x = __float2bfloat16(tile[2 * kp][n]);
        u.y = __float2bfloat16(tile[2 * kp + 1][n]);
        *(__hip_bfloat162*)(Wt + (size_t)(n0 + n) * K + k0 + 2 * kp) = u;
    }
}

// ---------------------------------------------------------------------------
// LayerNorm + (1+scale)*xn + shift, scale/shift = mod_table row + vec. D=2048.
// one block (256 thr) per row
// ---------------------------------------------------------------------------
__global__ __launch_bounds__(256) void ln_mod(
    const float* __restrict__ x, const float* __restrict__ table,
    const float* __restrict__ vec, int shiftRow, int scaleRow,
    __hip_bfloat16* __restrict__ out)
{
    const int D = 2048;
    int row = blockIdx.x, t = threadIdx.x;
    const float* xr = x + (size_t)row * D + t * 8;
    float4 a = *(const float4*)xr;
    float4 b = *(const float4*)(xr + 4);
    float xv[8] = {a.x, a.y, a.z, a.w, b.x, b.y, b.z, b.w};
    float s = 0.f, ss = 0.f;
#pragma unroll
    for (int j = 0; j < 8; ++j) { s += xv[j]; ss += xv[j] * xv[j]; }
#pragma unroll
    for (int m = 1; m < 64; m <<= 1) { s += __shfl_xor(s, m); ss += __shfl_xor(ss, m); }
    __shared__ float rs[4], rss[4];
    int w = t >> 6;
    if ((t & 63) == 0) { rs[w] = s; rss[w] = ss; }
    __syncthreads();
    s = rs[0] + rs[1] + rs[2] + rs[3];
    ss = rss[0] + rss[1] + rss[2] + rss[3];
    float mu = s * (1.f / D);
    float var = ss * (1.f / D) - mu * mu;
    float rstd = 1.f / sqrtf(var + 1e-6f);
    const float* sh = table + (size_t)shiftRow * D + t * 8;
    const float* sc = table + (size_t)scaleRow * D + t * 8;
    const float* vc = vec + t * 8;
    __align__(16) __hip_bfloat16 ob[8];
#pragma unroll
    for (int j = 0; j < 8; ++j) {
        float y = (xv[j] - mu) * rstd * (1.f + sc[j] + vc[j]) + (sh[j] + vc[j]);
        ob[j] = __float2bfloat16(y);
    }
    *(bf16x8*)(out + (size_t)row * D + t * 8) = *(const bf16x8*)ob;
}

// ---------------------------------------------------------------------------
// GEMM: C = A (MxK bf16) * Bt^T (Bt: NxK bf16) + epilogue
// EPI 0: out_f = acc + bias
// EPI 1: out_f = res + (acc + bias) * (modg + vecg)      (per-column gate)
// EPI 2: out_b = gelu_tanh(acc + bias)                    (bf16 out)
// tile 128x128, BK=32, 4 waves (2x2 of 64x64)
// grid: (N/128, M/128), block 256
// ---------------------------------------------------------------------------
template <int EPI>
__global__ __launch_bounds__(256) void gemm_bt(
    const __hip_bfloat16* __restrict__ A, const __hip_bfloat16* __restrict__ Bt,
    int M, int N, int K,
    const float* __restrict__ bias, const float* __restrict__ modg,
    const float* __restrict__ vecg, const float* __restrict__ res,
    float* __restrict__ outf, __hip_bfloat16* __restrict__ outb)
{
    __shared__ __align__(16) __hip_bfloat16 As[128 * 32];
    __shared__ __align__(16) __hip_bfloat16 Bs[128 * 32];
    int t = threadIdx.x, lane = t & 63, w = t >> 6;
    int bm = blockIdx.y, bn = blockIdx.x;
    int c = lane & 15, g = lane >> 4;

    f32x4 zero = {0.f, 0.f, 0.f, 0.f};
    f32x4 acc[4][4];
#pragma unroll
    for (int i = 0; i < 4; ++i)
#pragma unroll
        for (int j = 0; j < 4; ++j) acc[i][j] = zero;

    // staging coords: chunk = w*2+i covers rows [chunk*16, chunk*16+16)
    // LDS slot layout: element (row, ko) stored at slot = ko ^ ((row>>1)&3)
    const int nK = K >> 5;
    for (int kt = 0; kt < nK; ++kt) {
        int k0 = kt << 5;
#pragma unroll
        for (int i = 0; i < 2; ++i) {
            int chunk = w * 2 + i;
            int row = chunk * 16 + (lane >> 2);
            int ko = (lane & 3) ^ ((row >> 1) & 3);
            const __hip_bfloat16* ga = A + (size_t)(bm * 128 + row) * K + k0 + ko * 8;
            const __hip_bfloat16* gb = Bt + (size_t)(bn * 128 + row) * K + k0 + ko * 8;
            g2lds16(ga, As + chunk * 512);
            g2lds16(gb, Bs + chunk * 512);
        }
        __syncthreads();
        bf16x8 af[4], bfr[4];
#pragma unroll
        for (int x = 0; x < 4; ++x) {
            int ar = (w >> 1) * 64 + x * 16 + c;
            af[x] = *(const bf16x8*)(As + ar * 32 + ((g ^ ((ar >> 1) & 3)) * 8));
            int br = (w & 1) * 64 + x * 16 + c;
            bfr[x] = *(const bf16x8*)(Bs + br * 32 + ((g ^ ((br >> 1) & 3)) * 8));
        }
#pragma unroll
        for (int mi = 0; mi < 4; ++mi)
#pragma unroll
            for (int ni = 0; ni < 4; ++ni)
                acc[mi][ni] = mfma16(af[mi], bfr[ni], acc[mi][ni]);
        __syncthreads();
    }

    // epilogue: C row = bm*128 + (w>>1)*64 + mi*16 + g*4 + r ; col = bn*128 + (w&1)*64 + ni*16 + c
#pragma unroll
    for (int ni = 0; ni < 4; ++ni) {
        int col = bn * 128 + (w & 1) * 64 + ni * 16 + c;
        float bv = bias[col];
        float gv = 0.f;
        if (EPI == 1) gv = modg[col] + vecg[col];
#pragma unroll
        for (int mi = 0; mi < 4; ++mi) {
#pragma unroll
            for (int r = 0; r < 4; ++r) {
                int rowg = bm * 128 + (w >> 1) * 64 + mi * 16 + g * 4 + r;
                float v = acc[mi][ni][r] + bv;
                if (EPI == 0) {
                    outf[(size_t)rowg * N + col] = v;
                } else if (EPI == 1) {
                    outf[(size_t)rowg * N + col] = res[(size_t)rowg * N + col] + v * gv;
                } else {
                    float th = tanhf(0.7978845608028654f * (v + 0.044715f * v * v * v));
                    outb[(size_t)rowg * N + col] = __float2bfloat16(0.5f * v * (1.f + th));
                }
            }
        }
    }
}

// ---------------------------------------------------------------------------
// QK RMS-norm + RoPE (img only) + 1/sqrt(hd) fold into Q; V transposed.
// qkv layouts: [row][3*16*128]. Q,K out: [16][2304][128]; Vt: [16][128][2304]
// one wave per (l, h); block 256 = 4 waves; grid 2304*16/4 = 9216
// ---------------------------------------------------------------------------
__global__ __launch_bounds__(256) void qknorm_rope(
    const float* __restrict__ qkvI, const float* __restrict__ qkvT,
    const float* __restrict__ qnI, const float* __restrict__ knI,
    const float* __restrict__ qnT, const float* __restrict__ knT,
    const float* __restrict__ rope,
    __hip_bfloat16* __restrict__ Q, __hip_bfloat16* __restrict__ Kmat,
    __hip_bfloat16* __restrict__ Vt)
{
    const int L = 2304;
    int t = threadIdx.x, lane = t & 63, w = t >> 6;
    int wg = blockIdx.x * 4 + w;
    int l = wg >> 4, h = wg & 15;
    bool isImg = l < 2048;
    const float* src = isImg ? qkvI : qkvT;
    int row = isImg ? l : (l - 2048);
    const float* qn = isImg ? qnI : qnT;
    const float* kn = isImg ? knI : knT;
    int e = lane * 2;
    const float* pr = src + (size_t)row * 6144 + h * 128 + e;
    float2 q2 = *(const float2*)pr;
    float2 k2 = *(const float2*)(pr + 2048);
    float2 v2 = *(const float2*)(pr + 4096);
    float sq = q2.x * q2.x + q2.y * q2.y;
    float sk = k2.x * k2.x + k2.y * k2.y;
#pragma unroll
    for (int m = 1; m < 64; m <<= 1) { sq += __shfl_xor(sq, m); sk += __shfl_xor(sk, m); }
    float rq = 1.f / sqrtf(sq * (1.f / 128.f) + 1e-6f);
    float rk = 1.f / sqrtf(sk * (1.f / 128.f) + 1e-6f);
    float q0 = q2.x * rq * qn[e], q1 = q2.y * rq * qn[e + 1];
    float k0 = k2.x * rk * kn[e], k1 = k2.y * rk * kn[e + 1];
    if (isImg) {
        float co = rope[(size_t)l * 128 + lane];
        float si = rope[(size_t)l * 128 + 64 + lane];
        float a = q0 * co - q1 * si, b = q1 * co + q0 * si; q0 = a; q1 = b;
        a = k0 * co - k1 * si; b = k1 * co + k0 * si; k0 = a; k1 = b;
    }
    const float scl = 0.08838834764831845f; // 1/sqrt(128): fold attn scale into Q
    q0 *= scl; q1 *= scl;
    size_t qo = ((size_t)h * L + l) * 128 + e;
    __hip_bfloat162 qp; qp.x = __float2bfloat16(q0); qp.y = __float2bfloat16(q1);
    __hip_bfloat162 kp; kp.x = __float2bfloat16(k0); kp.y = __float2bfloat16(k1);
    *(__hip_bfloat162*)(Q + qo) = qp;
    *(__hip_bfloat162*)(Kmat + qo) = kp;
    Vt[((size_t)h * 128 + e) * L + l] = __float2bfloat16(v2.x);
    Vt[((size_t)h * 128 + e + 1) * L + l] = __float2bfloat16(v2.y);
}

// ---------------------------------------------------------------------------
// Flash attention. 1 wave = 16 q rows of one head. kv chunks of 32.
// S^T = mfma(K_tile, Q^T_tile): lane holds S^T[kv=g*4+r][q=c]; softmax per q=c.
// P staged via LDS to re-fragment as PV A-operand. O = P*V via Vt.
// out: [2304][2048] bf16 (head-major cols). grid 576 x 256thr.
// ---------------------------------------------------------------------------
__global__ __launch_bounds__(256) void attn_kernel(
    const __hip_bfloat16* __restrict__ Q, const __hip_bfloat16* __restrict__ Kmat,
    const __hip_bfloat16* __restrict__ Vt, __hip_bfloat16* __restrict__ O)
{
    const int L = 2304;
    __shared__ __align__(16) __hip_bfloat16 Plds[4][16][40];
    int t = threadIdx.x, lane = t & 63, w = t >> 6;
    int wg = blockIdx.x * 4 + w;
    int h = wg / 144, qt = wg % 144;
    int c = lane & 15, g = lane >> 4;

    const __hip_bfloat16* Qh = Q + ((size_t)h * L + qt * 16 + c) * 128;
    bf16x8 qf[4];
#pragma unroll
    for (int dc = 0; dc < 4; ++dc) qf[dc] = *(const bf16x8*)(Qh + dc * 32 + g * 8);

    const __hip_bfloat16* Kh = Kmat + (size_t)h * L * 128;
    const __hip_bfloat16* Vh = Vt + (size_t)h * 128 * L;

    float mrun = -INFINITY, lsum = 0.f;
    f32x4 zero = {0.f, 0.f, 0.f, 0.f};
    f32x4 acc[8];
#pragma unroll
    for (int i = 0; i < 8; ++i) acc[i] = zero;

    __hip_bfloat16* prow = &Plds[w][c][0];

    for (int kc = 0; kc < 72; ++kc) {
        int kv0 = kc * 32;
        f32x4 st0 = zero, st1 = zero;
#pragma unroll
        for (int dc = 0; dc < 4; ++dc) {
            bf16x8 ka = *(const bf16x8*)(Kh + (size_t)(kv0 + c) * 128 + dc * 32 + g * 8);
            bf16x8 kb = *(const bf16x8*)(Kh + (size_t)(kv0 + 16 + c) * 128 + dc * 32 + g * 8);
            st0 = mfma16(ka, qf[dc], st0);
            st1 = mfma16(kb, qf[dc], st1);
        }
        // softmax over this chunk (rows of S^T = kv, col = q = c)
        float cmax = st0[0];
#pragma unroll
        for (int r = 1; r < 4; ++r) cmax = fmaxf(cmax, st0[r]);
#pragma unroll
        for (int r = 0; r < 4; ++r) cmax = fmaxf(cmax, st1[r]);
        cmax = fmaxf(cmax, __shfl_xor(cmax, 16));
        cmax = fmaxf(cmax, __shfl_xor(cmax, 32));
        float mn = fmaxf(mrun, cmax);
        float sc = __expf(mrun - mn);
        float p[8];
#pragma unroll
        for (int r = 0; r < 4; ++r) {
            p[r] = __expf(st0[r] - mn);
            p[4 + r] = __expf(st1[r] - mn);
        }
        float cs = 0.f;
#pragma unroll
        for (int r = 0; r < 8; ++r) cs += p[r];
        cs += __shfl_xor(cs, 16);
        cs += __shfl_xor(cs, 32);
        lsum = lsum * sc + cs;
        mrun = mn;
        // rescale O by per-row factor (row q = g*4+r lives at lane q)
        float scr[4];
#pragma unroll
        for (int r = 0; r < 4; ++r) scr[r] = __shfl(sc, g * 4 + r);
#pragma unroll
        for (int dt = 0; dt < 8; ++dt)
#pragma unroll
            for (int r = 0; r < 4; ++r) acc[dt][r] *= scr[r];
        // stage P^T -> Plds[q][kv] (this lane: q=c, kv = {g*4..g*4+3, 16+g*4..})
        __hip_bfloat162 p01, p23, p45, p67;
        p01.x = __float2bfloat16(p[0]); p01.y = __float2bfloat16(p[1]);
        p23.x = __float2bfloat16(p[2]); p23.y = __float2bfloat16(p[3]);
        p45.x = __float2bfloat16(p[4]); p45.y = __float2bfloat16(p[5]);
        p67.x = __float2bfloat16(p[6]); p67.y = __float2bfloat16(p[7]);
        *(__hip_bfloat162*)(prow + 4 * g) = p01;
        *(__hip_bfloat162*)(prow + 4 * g + 2) = p23;
        *(__hip_bfloat162*)(prow + 16 + 4 * g) = p45;
        *(__hip_bfloat162*)(prow + 16 + 4 * g + 2) = p67;
        // PV: A-frag = Plds[q=c][kv=g*8..g*8+7]
        bf16x8 pa = *(const bf16x8*)(&Plds[w][c][g * 8]);
#pragma unroll
        for (int dt = 0; dt < 8; ++dt) {
            bf16x8 vb = *(const bf16x8*)(Vh + (size_t)(dt * 16 + c) * L + kv0 + g * 8);
            acc[dt] = mfma16(pa, vb, acc[dt]);
        }
    }
    // epilogue: O row q = g*4+r, col = dt*16 + c
    float linv[4];
#pragma unroll
    for (int r = 0; r < 4; ++r) linv[r] = 1.f / __shfl(lsum, g * 4 + r);
#pragma unroll
    for (int dt = 0; dt < 8; ++dt)
#pragma unroll
        for (int r = 0; r < 4; ++r)
            O[(size_t)(qt * 16 + g * 4 + r) * 2048 + h * 128 + dt * 16 + c] =
                __float2bfloat16(acc[dt][r] * linv[r]);
}

// ---------------------------------------------------------------------------
extern "C" void kernel_launch(void* const* d_in, const int* in_sizes, int n_in,
                              void* d_out, int out_size, void* d_ws, size_t ws_size,
                              hipStream_t stream)
{
    const float* img      = (const float*)d_in[0];
    const float* txt      = (const float*)d_in[1];
    const float* vec      = (const float*)d_in[2];
    const float* rope     = (const float*)d_in[3];
    const float* i_mod    = (const float*)d_in[4];
    const float* i_qkv_w  = (const float*)d_in[5];
    const float* i_qkv_b  = (const float*)d_in[6];
    const float* i_qn     = (const float*)d_in[7];
    const float* i_kn     = (const float*)d_in[8];
    const float* i_proj_w = (const float*)d_in[9];
    const float* i_proj_b = (const float*)d_in[10];
    const float* i_fc1_w  = (const float*)d_in[11];
    const float* i_fc1_b  = (const float*)d_in[12];
    const float* i_fc2_w  = (const float*)d_in[13];
    const float* i_fc2_b  = (const float*)d_in[14];
    const float* t_mod    = (const float*)d_in[15];
    const float* t_qkv_w  = (const float*)d_in[16];
    const float* t_qkv_b  = (const float*)d_in[17];
    const float* t_qn     = (const float*)d_in[18];
    const float* t_kn     = (const float*)d_in[19];
    const float* t_proj_w = (const float*)d_in[20];
    const float* t_proj_b = (const float*)d_in[21];
    const float* t_fc1_w  = (const float*)d_in[22];
    const float* t_fc1_b  = (const float*)d_in[23];
    const float* t_fc2_w  = (const float*)d_in[24];
    const float* t_fc2_b  = (const float*)d_in[25];
    float* out = (float*)d_out;

    char* p = (char*)d_ws;
    auto alloc = [&](size_t n) { char* r = p; p += (n + 255) & ~(size_t)255; return r; };
    typedef __hip_bfloat16 bf;
    bf* WqkvI = (bf*)alloc((size_t)6144 * 2048 * 2);
    bf* WprojI = (bf*)alloc((size_t)2048 * 2048 * 2);
    bf* Wfc1I = (bf*)alloc((size_t)8192 * 2048 * 2);
    bf* Wfc2I = (bf*)alloc((size_t)2048 * 8192 * 2);
    bf* WqkvT = (bf*)alloc((size_t)6144 * 2048 * 2);
    bf* WprojT = (bf*)alloc((size_t)2048 * 2048 * 2);
    bf* Wfc1T = (bf*)alloc((size_t)8192 * 2048 * 2);
    bf* Wfc2T = (bf*)alloc((size_t)2048 * 8192 * 2);
    bf* mI = (bf*)alloc((size_t)2048 * 2048 * 2);
    bf* mT = (bf*)alloc((size_t)256 * 2048 * 2);
    float* qkvI = (float*)alloc((size_t)2048 * 6144 * 4);
    float* qkvT = (float*)alloc((size_t)256 * 6144 * 4);
    bf* Qb = (bf*)alloc((size_t)16 * 2304 * 128 * 2);
    bf* Kb = (bf*)alloc((size_t)16 * 2304 * 128 * 2);
    bf* Vtb = (bf*)alloc((size_t)16 * 128 * 2304 * 2);
    bf* AOb = (bf*)alloc((size_t)2304 * 2048 * 2);
    float* X1I = (float*)alloc((size_t)2048 * 2048 * 4);
    float* X1T = (float*)alloc((size_t)256 * 2048 * 4);
    bf* hI = (bf*)alloc((size_t)2048 * 8192 * 2);
    bf* hT = (bf*)alloc((size_t)256 * 8192 * 2);

    dim3 blk(256);
    // weight convert+transpose (grid: N/64, K/64)
    transpose_cvt<<<dim3(96, 32), blk, 0, stream>>>(i_qkv_w, WqkvI, 2048, 6144);
    transpose_cvt<<<dim3(32, 32), blk, 0, stream>>>(i_proj_w, WprojI, 2048, 2048);
    transpose_cvt<<<dim3(128, 32), blk, 0, stream>>>(i_fc1_w, Wfc1I, 2048, 8192);
    transpose_cvt<<<dim3(32, 128), blk, 0, stream>>>(i_fc2_w, Wfc2I, 8192, 2048);
    transpose_cvt<<<dim3(96, 32), blk, 0, stream>>>(t_qkv_w, WqkvT, 2048, 6144);
    transpose_cvt<<<dim3(32, 32), blk, 0, stream>>>(t_proj_w, WprojT, 2048, 2048);
    transpose_cvt<<<dim3(128, 32), blk, 0, stream>>>(t_fc1_w, Wfc1T, 2048, 8192);
    transpose_cvt<<<dim3(32, 128), blk, 0, stream>>>(t_fc2_w, Wfc2T, 8192, 2048);

    // LN1 + modulation
    ln_mod<<<2048, blk, 0, stream>>>(img, i_mod, vec, 0, 1, mI);
    ln_mod<<<256, blk, 0, stream>>>(txt, t_mod, vec, 0, 1, mT);

    // QKV GEMMs
    gemm_bt<0><<<dim3(48, 16), blk, 0, stream>>>(mI, WqkvI, 2048, 6144, 2048,
        i_qkv_b, nullptr, nullptr, nullptr, qkvI, nullptr);
    gemm_bt<0><<<dim3(48, 2), blk, 0, stream>>>(mT, WqkvT, 256, 6144, 2048,
        t_qkv_b, nullptr, nullptr, nullptr, qkvT, nullptr);

    // RMS norm + RoPE + pack Q/K/Vt
    qknorm_rope<<<9216, blk, 0, stream>>>(qkvI, qkvT, i_qn, i_kn, t_qn, t_kn,
                                          rope, Qb, Kb, Vtb);

    // attention
    attn_kernel<<<576, blk, 0, stream>>>(Qb, Kb, Vtb, AOb);

    // proj + gate + residual
    gemm_bt<1><<<dim3(16, 16), blk, 0, stream>>>(AOb, WprojI, 2048, 2048, 2048,
        i_proj_b, i_mod + 2 * 2048, vec, img, X1I, nullptr);
    gemm_bt<1><<<dim3(16, 2), blk, 0, stream>>>(AOb + (size_t)2048 * 2048, WprojT,
        256, 2048, 2048, t_proj_b, t_mod + 2 * 2048, vec, txt, X1T, nullptr);

    // LN2 + modulation (reuse m buffers)
    ln_mod<<<2048, blk, 0, stream>>>(X1I, i_mod, vec, 3, 4, mI);
    ln_mod<<<256, blk, 0, stream>>>(X1T, t_mod, vec, 3, 4, mT);

    // FC1 + gelu
    gemm_bt<2><<<dim3(64, 16), blk, 0, stream>>>(mI, Wfc1I, 2048, 8192, 2048,
        i_fc1_b, nullptr, nullptr, nullptr, nullptr, hI);
    gemm_bt<2><<<dim3(64, 2), blk, 0, stream>>>(mT, Wfc1T, 256, 8192, 2048,
        t_fc1_b, nullptr, nullptr, nullptr, nullptr, hT);

    // FC2 + gate + residual -> d_out
    gemm_bt<1><<<dim3(16, 16), blk, 0, stream>>>(hI, Wfc2I, 2048, 2048, 8192,
        i_fc2_b, i_mod + 5 * 2048, vec, X1I, out, nullptr);
    gemm_bt<1><<<dim3(16, 2), blk, 0, stream>>>(hT, Wfc2T, 256, 2048, 8192,
        t_fc2_b, t_mod + 5 * 2048, vec, X1T, out + (size_t)2048 * 2048, nullptr);
}